// Round 6
// baseline (476.465 us; speedup 1.0000x reference)
//
#include <hip/hip_runtime.h>

#define H 128
#define L 256
#define SB 8       // sequences per block
#define NBLK 256   // 2048/SB -> one block per CU
#define NTHR 512   // 8 waves; wave w owns gate-cols 16w..16w+15 of each gate tile

typedef _Float16 f16x8 __attribute__((ext_vector_type(8)));
typedef float f32x4 __attribute__((ext_vector_type(4)));

#define MFMA(accv, av, bv) accv = __builtin_amdgcn_mfma_f32_16x16x32_f16(av, bv, accv, 0, 0, 0)

__device__ __forceinline__ float fsig(float x) {
  return __builtin_amdgcn_rcpf(1.f + __builtin_amdgcn_exp2f(-1.44269504089f * x));
}
__device__ __forceinline__ float ftanh(float x) {
  return 2.f * __builtin_amdgcn_rcpf(1.f + __builtin_amdgcn_exp2f(-2.88539008178f * x)) - 1.f;
}

// Skewed pipeline: phase t computes h1(t) = L0(x(t), h1(t-1)) and
// h2(t-1) = L1(h1(t-1), h2(t-2)); one barrier per phase, 257 phases.
// R5: Whh1 b-frags PREFETCHED to registers at phase start (whh1t, 64 VGPR)
// so the 16 LDS reads stream under the 32 register-fed L0/L1a MFMAs instead
// of serializing read->MFMA 16 times (R4: phase ~= LDS + MFMA, no overlap).
// Seq->MFMA-row map: seq s at row 4*(s>>1)+(s&1); each lane owns 2 valid rows.
// LDS f16 tiles swizzled: (row,k) -> row*128 + (k^((row&7)<<3)).

__global__ __launch_bounds__(NTHR, 2) void lstm_kernel(
    const float* __restrict__ xg,
    const float* __restrict__ Wih0, const float* __restrict__ Whh0,
    const float* __restrict__ bih0, const float* __restrict__ bhh0,
    const float* __restrict__ Wih1, const float* __restrict__ Whh1,
    const float* __restrict__ bih1, const float* __restrict__ bhh1,
    const float* __restrict__ W1,   const float* __restrict__ b1v,
    const float* __restrict__ W2,   const float* __restrict__ b2v,
    const float* __restrict__ abias,
    float* __restrict__ out_scores)
{
  __shared__ __align__(16) _Float16 Whh1_s[512 * H];   // 128 KB, row-swizzled
  __shared__ __align__(16) float    x_s[L * SB];       // 8 KB, [t][s]
  __shared__ __align__(16) _Float16 h1_s[2][16 * H];   // 8 KB, double-buffered
  __shared__ __align__(16) _Float16 h2_s[2][16 * H];   // 8 KB

  const int tid  = threadIdx.x;
  const int lane = tid & 63;
  const int w    = tid >> 6;
  const int l15  = lane & 15;
  const int lhi  = lane >> 4;
  const int sb   = blockIdx.x * SB;

  // ---- stage x transposed [t][s] ----
  for (int i = tid; i < SB * L; i += NTHR) {
    int s = i >> 8, t = i & 255;
    x_s[t * SB + s] = xg[(sb + s) * L + t];
  }
  // ---- stage W_hh1 as f16, swizzled ----
  for (int i = tid; i < 512 * H; i += NTHR) {
    int r = i >> 7, k = i & 127;
    Whh1_s[(r << 7) + (k ^ ((r & 7) << 3))] = (_Float16)Whh1[i];
  }
  // ---- zero h state, both buffers ----
  for (int i = tid; i < 16 * H; i += NTHR) {
    h1_s[0][i] = (_Float16)0.f; h1_s[1][i] = (_Float16)0.f;
    h2_s[0][i] = (_Float16)0.f; h2_s[1][i] = (_Float16)0.f;
  }

  // ---- per-wave register weight B-fragments (Whh0, Wih1) ----
  f16x8 whh0f[4][4], wih1f[4][4];
  float b0r[4], b1r[4], w0r[4];
  #pragma unroll
  for (int n = 0; n < 4; ++n) {
    const int c = (n << 7) + (w << 4) + l15;
    b0r[n] = bih0[c] + bhh0[c];
    b1r[n] = bih1[c] + bhh1[c];
    w0r[n] = Wih0[c];
    #pragma unroll
    for (int kk = 0; kk < 4; ++kk) {
      const float* p0 = Whh0 + c * H + (kk << 5) + (lhi << 3);
      const float* p1 = Wih1 + c * H + (kk << 5) + (lhi << 3);
      f16x8 f0, f1;
      #pragma unroll
      for (int j = 0; j < 8; ++j) { f0[j] = (_Float16)p0[j]; f1[j] = (_Float16)p1[j]; }
      whh0f[n][kk] = f0; wih1f[n][kk] = f1;
    }
  }

  float c1[2] = {0.f, 0.f}, c2[2] = {0.f, 0.f};
  const int colh  = (w << 4) | l15;
  const int rown0 = lhi << 2;           // owned rows: rown0, rown0+1
  const int so0   = lhi << 1;           // owned seqs: so0, so0+1
  const int arow  = l15 << 7;           // A-frag row base
  const int aswz  = (l15 & 7) << 3;     // swizzle for row l15 / Whh1 row
  int wrow[4];
  #pragma unroll
  for (int n = 0; n < 4; ++n) wrow[n] = ((n << 7) + colh) << 7;

  __syncthreads();

  #pragma unroll 1
  for (int t = 0; t <= L; ++t) {
    const int pw = t & 1;        // h1 write buf; h2 READ buf (holds h2(t-2))
    const int pr = pw ^ 1;       // h1 read buf (h1(t-1)); h2 write buf (h2(t-1))

    // ---- issue ALL LDS reads up front: a-frags + Whh1 b-frags to regs ----
    f16x8 a1f[4], a2f[4];
    #pragma unroll
    for (int kk = 0; kk < 4; ++kk) {
      const int kb = (kk << 5) + (lhi << 3);
      a1f[kk] = *(const f16x8*)&h1_s[pr][arow + (kb ^ aswz)];
      a2f[kk] = *(const f16x8*)&h2_s[pw][arow + (kb ^ aswz)];
    }
    f16x8 whh1t[4][4];
    #pragma unroll
    for (int kk = 0; kk < 4; ++kk) {
      const int kb = (kk << 5) + (lhi << 3);
      #pragma unroll
      for (int n = 0; n < 4; ++n)
        whh1t[kk][n] = *(const f16x8*)&Whh1_s[wrow[n] + (kb ^ aswz)];
    }

    f32x4 acc0[4], acc1[4];
    #pragma unroll
    for (int n = 0; n < 4; ++n) {
      acc0[n] = (f32x4){0.f, 0.f, 0.f, 0.f};
      acc1[n] = (f32x4){0.f, 0.f, 0.f, 0.f};
    }

    // L0 + L1a: 32 register-fed MFMAs (need only a1f) — cover whh1t's LDS pipe
    #pragma unroll
    for (int kk = 0; kk < 4; ++kk) {
      MFMA(acc0[0], a1f[kk], whh0f[0][kk]);
      MFMA(acc0[1], a1f[kk], whh0f[1][kk]);
      MFMA(acc0[2], a1f[kk], whh0f[2][kk]);
      MFMA(acc0[3], a1f[kk], whh0f[3][kk]);
      MFMA(acc1[0], a1f[kk], wih1f[0][kk]);
      MFMA(acc1[1], a1f[kk], wih1f[1][kk]);
      MFMA(acc1[2], a1f[kk], wih1f[2][kk]);
      MFMA(acc1[3], a1f[kk], wih1f[3][kk]);
    }
    // L1b: 16 MFMAs from prefetched registers
    #pragma unroll
    for (int kk = 0; kk < 4; ++kk) {
      MFMA(acc1[0], a2f[kk], whh1t[kk][0]);
      MFMA(acc1[1], a2f[kk], whh1t[kk][1]);
      MFMA(acc1[2], a2f[kk], whh1t[kk][2]);
      MFMA(acc1[3], a2f[kk], whh1t[kk][3]);
    }

    // ---- L0 activation -> h1(t) ----
    if (t < L) {
      const float2 xv = *(const float2*)&x_s[t * SB + so0];
      float h1n[2];
      #pragma unroll
      for (int r = 0; r < 2; ++r) {
        const float x0 = r ? xv.y : xv.x;
        float ig = fsig (acc0[0][r] + x0 * w0r[0] + b0r[0]);
        float fg = fsig (acc0[1][r] + x0 * w0r[1] + b0r[1]);
        float gg = ftanh(acc0[2][r] + x0 * w0r[2] + b0r[2]);
        float og = fsig (acc0[3][r] + x0 * w0r[3] + b0r[3]);
        float c = fg * c1[r] + ig * gg;
        c1[r] = c;
        h1n[r] = og * ftanh(c);
      }
      #pragma unroll
      for (int r = 0; r < 2; ++r) {
        const int row = rown0 + r;
        h1_s[pw][(row << 7) + (colh ^ ((row & 7) << 3))] = (_Float16)h1n[r];
      }
    }
    // ---- L1 activation -> h2(t-1) ----
    if (t > 0) {
      float h2n[2];
      #pragma unroll
      for (int r = 0; r < 2; ++r) {
        float ig = fsig (acc1[0][r] + b1r[0]);
        float fg = fsig (acc1[1][r] + b1r[1]);
        float gg = ftanh(acc1[2][r] + b1r[2]);
        float og = fsig (acc1[3][r] + b1r[3]);
        float c = fg * c2[r] + ig * gg;
        c2[r] = c;
        h2n[r] = og * ftanh(c);
      }
      #pragma unroll
      for (int r = 0; r < 2; ++r) {
        const int row = rown0 + r;
        h2_s[pr][(row << 7) + (colh ^ ((row & 7) << 3))] = (_Float16)h2n[r];
      }
    }
    __syncthreads();   // publish h1(t), h2(t-1); also orders buffer reuse
  }

  // ================= MLP head =================
  // final h2 = h2(L-1), in h2_s[1]
  float* W1t = (float*)Whh1_s;          // [k][j] transposed fp32, 64 KB
  for (int i = tid; i < H * H; i += NTHR) {
    int j = i >> 7, k = i & 127;
    W1t[(k << 7) + j] = W1[i];
  }
  __syncthreads();
  {
    const int s   = w;                           // wave w <-> seq w
    const int row = ((s >> 1) << 2) | (s & 1);   // seq->row map
    float a0 = 0.f, a1 = 0.f;
    for (int k = 0; k < H; ++k) {
      float hv = (float)h2_s[1][(row << 7) + (k ^ ((row & 7) << 3))];  // broadcast
      a0 += hv * W1t[(k << 7) + lane];
      a1 += hv * W1t[(k << 7) + lane + 64];
    }
    a0 = fmaxf(a0 + b1v[lane], 0.f);
    a1 = fmaxf(a1 + b1v[lane + 64], 0.f);
    float part = a0 * W2[lane] + a1 * W2[lane + 64];
    #pragma unroll
    for (int off = 32; off >= 1; off >>= 1) part += __shfl_xor(part, off, 64);
    if (lane == 0)
      out_scores[sb + s] = part + b2v[0] + abias[(sb + s) & 63];
  }
}

// softmax over each row of 64 (one wave per row), in-place on d_out
__global__ void softmax_kernel(float* __restrict__ out) {
  const int b = blockIdx.x, n = threadIdx.x;
  float v = out[(b << 6) + n];
  float m = v;
  #pragma unroll
  for (int off = 32; off >= 1; off >>= 1) m = fmaxf(m, __shfl_xor(m, off, 64));
  float e = __builtin_amdgcn_exp2f((v - m) * 1.44269504089f);
  float s = e;
  #pragma unroll
  for (int off = 32; off >= 1; off >>= 1) s += __shfl_xor(s, off, 64);
  out[(b << 6) + n] = e / s;
}

extern "C" void kernel_launch(void* const* d_in, const int* in_sizes, int n_in,
                              void* d_out, int out_size, void* d_ws, size_t ws_size,
                              hipStream_t stream) {
  (void)in_sizes; (void)n_in; (void)d_ws; (void)ws_size; (void)out_size;
  const float* xg   = (const float*)d_in[0];
  const float* Wih0 = (const float*)d_in[1];
  const float* Whh0 = (const float*)d_in[2];
  const float* bih0 = (const float*)d_in[3];
  const float* bhh0 = (const float*)d_in[4];
  const float* Wih1 = (const float*)d_in[5];
  const float* Whh1 = (const float*)d_in[6];
  const float* bih1 = (const float*)d_in[7];
  const float* bhh1 = (const float*)d_in[8];
  const float* W1   = (const float*)d_in[9];
  const float* b1   = (const float*)d_in[10];
  const float* W2   = (const float*)d_in[11];
  const float* b2   = (const float*)d_in[12];
  const float* ab   = (const float*)d_in[13];
  float* out = (float*)d_out;

  lstm_kernel<<<NBLK, NTHR, 0, stream>>>(xg, Wih0, Whh0, bih0, bhh0,
                                         Wih1, Whh1, bih1, bhh1,
                                         W1, b1, W2, b2, ab, out);
  softmax_kernel<<<32, 64, 0, stream>>>(out);
}